// Round 8
// baseline (10071.619 us; speedup 1.0000x reference)
//
#include <hip/hip_runtime.h>
#include <stdint.h>

// ===================== Round 8 =====================
// Barrier-free restructure: W-frags stream straight from GLOBAL
// (L2-resident packed wp) into registers -- NO W in LDS, NO barriers
// in the main loop (hst/xs staging is wave-private; one syncthreads
// after bias init only). LDS pipe keeps only activations (~16k cyc),
// VMEM/L1 carries W (~16k cyc), both under MFMA 19.9k cyc/eval/CU.
// 16x16x32 MFMA (R7's 32x32 chain-latency regression reverted).
// xb state moved to LDS (xsb) to fund W-in-reg budget.
// Predict: 1100-1400us, MfmaUtil 45-60, FETCH ~0.3GB, absmax 0.03125.
// ===================================================

typedef _Float16 half8 __attribute__((ext_vector_type(8)));
typedef float f32x4 __attribute__((ext_vector_type(4)));

#define XSTR 136  // shorts per x row (128 + 8 pad), 272B, rows 16B-aligned
#define HSTR 40   // shorts per h row (32 + 8 pad), 80B, rows 16B-aligned

static __device__ __forceinline__ unsigned short f2h(float x) {
  union { _Float16 h; unsigned short u; } cv;
  cv.h = (_Float16)x;
  return cv.u;
}
static __device__ __forceinline__ float h2f(unsigned short u) {
  union { unsigned short u; _Float16 h; } cv;
  cv.u = u;
  return (float)cv.h;
}
static __device__ __forceinline__ uint64_t pack4(float a, float b, float c, float d) {
  union { _Float16 h[4]; uint64_t q; } cv;
  cv.h[0] = (_Float16)a; cv.h[1] = (_Float16)b;
  cv.h[2] = (_Float16)c; cv.h[3] = (_Float16)d;
  return cv.q;
}

// Prepack W1^T / W2^T as 16x16x32 MFMA A-frag streams (identical to R6).
// A-frag: lane l holds A[m = l&15][k = (l>>4)*8 + j], 8 halves = 16B.
// 16 chunks of 32 hid; chunk c at wp + c*16384:
//  [0,8K):  W1T frags f = T*4 + ks (T: 2 hid-tiles, ks: 4 of K_in=128)
//  [8K,16K): W2T frags f = 8 + O (O: 8 out-tiles, K_hid = 32 chunk-local)
__global__ void pack_w(const float* __restrict__ W1, const float* __restrict__ W2,
                       unsigned short* __restrict__ wp) {
  int id = blockIdx.x * 256 + threadIdx.x;  // 0..16383
  int lane = id & 63, fid = (id >> 6) & 255;
  int g = lane >> 4, lm = lane & 15;
  int c = fid >> 4, f = fid & 15;
  if (f < 8) {
    int T = f >> 2, ks = f & 3;
    int hid = c * 32 + T * 16 + lm;
#pragma unroll
    for (int j = 0; j < 8; ++j) {
      int kin = ks * 32 + g * 8 + j;
      wp[fid * 512 + lane * 8 + j] = f2h(W1[kin * 512 + hid]);
    }
  } else {
    int O = f - 8;
    int of = O * 16 + lm;
#pragma unroll
    for (int j = 0; j < 8; ++j) {
      int kh = c * 32 + g * 8 + j;
      wp[fid * 512 + lane * 8 + j] = f2h(W2[kh * 128 + of]);
    }
  }
}

__global__ __launch_bounds__(512, 2) void node_rk4(
    const float* __restrict__ x0, const float* __restrict__ b1,
    const float* __restrict__ b2, const unsigned short* __restrict__ wp,
    float* __restrict__ out) {
  // LDS (162,304 B): xsb (x base, fp16) + xsc (x_in current stage, fp16)
  // + hst (h bounce) + biases. All activation staging is WAVE-PRIVATE.
  __shared__ __align__(16) unsigned short xsb[8][32][XSTR];
  __shared__ __align__(16) unsigned short xsc[8][32][XSTR];
  __shared__ __align__(16) unsigned short hst[8][32][HSTR];
  __shared__ float b1s[512];
  __shared__ float b2s[128];

  const int tid = threadIdx.x;
  const int w = tid >> 6, lane = tid & 63;
  const int g = lane >> 4, lm = lane & 15;

  b1s[tid] = b1[tid];
  if (tid < 128) b2s[tid] = b2[tid];

  // State: lane (g,lm) holds batch col nt*16+lm, feature rows O*16+4g+j.
  // xa (f32 accumulator) in regs; xb (step base) lives in xsb as fp16.
  const int rbase = blockIdx.x * 256 + w * 32;
  f32x4 xa[2][8];
#pragma unroll
  for (int nt = 0; nt < 2; ++nt)
#pragma unroll
    for (int O = 0; O < 8; ++O) {
      f32x4 v = *(const f32x4*)&x0[(rbase + nt * 16 + lm) * 128 + O * 16 + 4 * g];
      xa[nt][O] = v;
      *(uint64_t*)&xsb[w][nt * 16 + lm][O * 16 + 4 * g] = pack4(v[0], v[1], v[2], v[3]);
    }
  __syncthreads();  // the ONLY barrier: b1s/b2s are cross-wave

#pragma unroll 1
  for (int it = 0; it < 80; ++it) {
    const int s = it & 3;
    const float wgt = (s == 0 || s == 3) ? (0.1f / 6.0f) : (0.1f / 3.0f);
    const float alph = (s < 2) ? 0.05f : 0.1f;

    // x_in source: stage 0 reads the step base (xsb), else current (xsc).
    const unsigned short(*xsrc)[XSTR] = (s == 0) ? xsb[w] : xsc[w];

    // x^T B-frags (K_in=128), held for the whole eval.
    half8 X1[2][4];
#pragma unroll
    for (int nt = 0; nt < 2; ++nt)
#pragma unroll
      for (int ks = 0; ks < 4; ++ks)
        X1[nt][ks] = *(const half8*)&xsrc[nt * 16 + lm][ks * 32 + g * 8];

    f32x4 yacc[2][8];
#pragma unroll
    for (int nt = 0; nt < 2; ++nt)
#pragma unroll
      for (int O = 0; O < 8; ++O) yacc[nt][O] = f32x4{0.f, 0.f, 0.f, 0.f};

#pragma unroll
    for (int c = 0; c < 16; ++c) {
      // W-frags for this chunk: straight from global (L2-resident stream),
      // 16 x b128 per wave. No LDS, no barrier. Issued as one burst;
      // consumed oldest-first (GEMM1 uses f0..7, GEMM2 f8..15).
      const char* wc = (const char*)wp + c * 16384 + lane * 16;
      half8 Wf[16];
#pragma unroll
      for (int f = 0; f < 16; ++f) Wf[f] = *(const half8*)(wc + f * 1024);

      // GEMM1': h^T (hid 32 x batch 32) = W1T(c) x x^T.
#pragma unroll
      for (int T = 0; T < 2; ++T) {
        f32x4 h0 = {0.f, 0.f, 0.f, 0.f}, h1 = {0.f, 0.f, 0.f, 0.f};
#pragma unroll
        for (int ks = 0; ks < 4; ++ks) {
          h0 = __builtin_amdgcn_mfma_f32_16x16x32_f16(Wf[T * 4 + ks], X1[0][ks], h0, 0, 0, 0);
          h1 = __builtin_amdgcn_mfma_f32_16x16x32_f16(Wf[T * 4 + ks], X1[1][ks], h1, 0, 0, 0);
        }
        f32x4 bb = *(const f32x4*)&b1s[c * 32 + T * 16 + 4 * g];
        uint64_t p0 = pack4(fmaxf(h0[0] + bb[0], 0.f), fmaxf(h0[1] + bb[1], 0.f),
                            fmaxf(h0[2] + bb[2], 0.f), fmaxf(h0[3] + bb[3], 0.f));
        uint64_t p1 = pack4(fmaxf(h1[0] + bb[0], 0.f), fmaxf(h1[1] + bb[1], 0.f),
                            fmaxf(h1[2] + bb[2], 0.f), fmaxf(h1[3] + bb[3], 0.f));
        *(uint64_t*)&hst[w][lm][T * 16 + 4 * g] = p0;
        *(uint64_t*)&hst[w][16 + lm][T * 16 + 4 * g] = p1;
      }

      // h^T B-frags (wave-private bounce; compiler inserts lgkm wait).
      half8 Hp0 = *(const half8*)&hst[w][lm][g * 8];
      half8 Hp1 = *(const half8*)&hst[w][16 + lm][g * 8];

      // GEMM2': y^T += W2T(c) x h^T(c).
#pragma unroll
      for (int O = 0; O < 8; ++O) {
        yacc[0][O] = __builtin_amdgcn_mfma_f32_16x16x32_f16(Wf[8 + O], Hp0, yacc[0][O], 0, 0, 0);
        yacc[1][O] = __builtin_amdgcn_mfma_f32_16x16x32_f16(Wf[8 + O], Hp1, yacc[1][O], 0, 0, 0);
      }
    }

    // RK4 combine. Stage 3: new base -> xsb. Else: x_in = xb + alph*k -> xsc.
#pragma unroll
    for (int nt = 0; nt < 2; ++nt)
#pragma unroll
      for (int O = 0; O < 8; ++O) {
        f32x4 bb2 = *(const f32x4*)&b2s[O * 16 + 4 * g];
        f32x4 k = yacc[nt][O];
#pragma unroll
        for (int j = 0; j < 4; ++j) k[j] += bb2[j];
        xa[nt][O] += wgt * k;
        if (s == 3) {
          f32x4 v = xa[nt][O];
          *(uint64_t*)&xsb[w][nt * 16 + lm][O * 16 + 4 * g] =
              pack4(v[0], v[1], v[2], v[3]);
        } else {
          uint64_t xq = *(const uint64_t*)&xsb[w][nt * 16 + lm][O * 16 + 4 * g];
          union { uint64_t q; unsigned short u[4]; } xb;
          xb.q = xq;
          *(uint64_t*)&xsc[w][nt * 16 + lm][O * 16 + 4 * g] =
              pack4(h2f(xb.u[0]) + alph * k[0], h2f(xb.u[1]) + alph * k[1],
                    h2f(xb.u[2]) + alph * k[2], h2f(xb.u[3]) + alph * k[3]);
        }
      }
  }

#pragma unroll
  for (int nt = 0; nt < 2; ++nt)
#pragma unroll
    for (int O = 0; O < 8; ++O)
      *(f32x4*)&out[(rbase + nt * 16 + lm) * 128 + O * 16 + 4 * g] = xa[nt][O];
}

extern "C" void kernel_launch(void* const* d_in, const int* in_sizes, int n_in,
                              void* d_out, int out_size, void* d_ws, size_t ws_size,
                              hipStream_t stream) {
  const float* x0 = (const float*)d_in[0];
  const float* W1 = (const float*)d_in[1];
  const float* b1 = (const float*)d_in[2];
  const float* W2 = (const float*)d_in[3];
  const float* b2 = (const float*)d_in[4];
  float* out = (float*)d_out;

  unsigned short* wp = (unsigned short*)d_ws;  // 256 frags * 1KB = 256KB

  pack_w<<<64, 256, 0, stream>>>(W1, W2, wp);
  node_rk4<<<256, 512, 0, stream>>>(x0, b1, b2, wp, out);
}

// Round 9
// 4411.330 us; speedup vs baseline: 2.2831x; 2.2831x over previous
//
#include <hip/hip_runtime.h>
#include <stdint.h>

// ===================== Round 9 =====================
// R6 schedule (ring-4 W in LDS via global_load_lds, counted vmcnt,
// GEMM2 one chunk behind, per-chunk s_barrier) restructured to
// batch-64/wave x 4 waves x 256 blocks (1 wave/SIMD, ~450 VGPR):
// each W-frag read feeds 4 MFMAs -> W LDS traffic per CU halves
// (2MB -> 1MB/eval). XOR swizzle ((r&8)<<1) on xs/hst rows kills
// lm/lm+8 bank collisions. R8's W-from-global reverted (20GB HBM).
// Predict: 1500-1800us, MfmaUtil 33-42, conflicts <3e7, absmax 0.03125.
// ===================================================

typedef _Float16 half8 __attribute__((ext_vector_type(8)));
typedef float f32x4 __attribute__((ext_vector_type(4)));
typedef __attribute__((address_space(3))) char lchar;
typedef __attribute__((address_space(1))) char gchar;

static __device__ __forceinline__ void gload_lds16(const void* g, void* l) {
  __builtin_amdgcn_global_load_lds((const gchar*)g, (lchar*)l, 16, 0, 0);
}

static __device__ __forceinline__ unsigned short f2h(float x) {
  union { _Float16 h; unsigned short u; } cv;
  cv.h = (_Float16)x;
  return cv.u;
}
static __device__ __forceinline__ float h2f(unsigned short u) {
  union { unsigned short u; _Float16 h; } cv;
  cv.u = u;
  return (float)cv.h;
}
static __device__ __forceinline__ uint64_t pack4(float a, float b, float c, float d) {
  union { _Float16 h[4]; uint64_t q; } cv;
  cv.h[0] = (_Float16)a; cv.h[1] = (_Float16)b;
  cv.h[2] = (_Float16)c; cv.h[3] = (_Float16)d;
  return cv.q;
}

// Swizzled byte offsets (bit-4 XOR per 8-row group; bijective, keeps
// b64/b128 alignment; write & read use the same map).
static __device__ __forceinline__ int xs_off(int r, int feat) {
  return (r * 272 + feat * 2) ^ ((r & 8) << 1);
}
static __device__ __forceinline__ int hs_off(int r, int hid) {
  return (r * 80 + hid * 2) ^ ((r & 8) << 1);
}

// Prepack W1^T / W2^T as 16x16x32 MFMA A-frag streams (identical to R6).
// A-frag: lane l holds A[m = l&15][k = (l>>4)*8 + j], 8 halves = 16B.
// 16 chunks of 32 hid; chunk c at wp + c*16384:
//  [0,8K):  W1T frags f = T*4 + ks (T: 2 hid-tiles, ks: 4 of K_in=128)
//  [8K,16K): W2T frags f = 8 + O (O: 8 out-tiles, K_hid = 32 chunk-local)
__global__ void pack_w(const float* __restrict__ W1, const float* __restrict__ W2,
                       unsigned short* __restrict__ wp) {
  int id = blockIdx.x * 256 + threadIdx.x;  // 0..16383
  int lane = id & 63, fid = (id >> 6) & 255;
  int g = lane >> 4, lm = lane & 15;
  int c = fid >> 4, f = fid & 15;
  if (f < 8) {
    int T = f >> 2, ks = f & 3;
    int hid = c * 32 + T * 16 + lm;
#pragma unroll
    for (int j = 0; j < 8; ++j) {
      int kin = ks * 32 + g * 8 + j;
      wp[fid * 512 + lane * 8 + j] = f2h(W1[kin * 512 + hid]);
    }
  } else {
    int O = f - 8;
    int of = O * 16 + lm;
#pragma unroll
    for (int j = 0; j < 8; ++j) {
      int kh = c * 32 + g * 8 + j;
      wp[fid * 512 + lane * 8 + j] = f2h(W2[kh * 128 + of]);
    }
  }
}

__global__ __launch_bounds__(256, 1) void node_rk4(
    const float* __restrict__ x0, const float* __restrict__ b1,
    const float* __restrict__ b2, const unsigned short* __restrict__ wp,
    float* __restrict__ out) {
  // LDS: 64K W ring + 68K xs (4 waves x 64 rows x 272B) + 20K hst
  // (4 x 64 x 80B) + biases = 158,208 B. 1 block/CU.
  __shared__ char Wbuf[4][16384];
  __shared__ __align__(16) char xsm[4][64 * 272];
  __shared__ __align__(16) char hsm[4][64 * 80];
  __shared__ float b1s[512];
  __shared__ float b2s[128];

  const int tid = threadIdx.x;
  const int w = tid >> 6, lane = tid & 63;
  const int g = lane >> 4, lm = lane & 15;
  char* xsw = xsm[w];
  char* hsw = hsm[w];

  b1s[tid] = b1[tid];
  b1s[tid + 256] = b1[tid + 256];
  if (tid < 128) b2s[tid] = b2[tid];

  // State: lane (g,lm) holds batch col nt*16+lm (nt 0..3), feature rows
  // O*16 + 4g + j. xa fp32 accumulator; xbh packed-fp16 step base.
  const int rbase = blockIdx.x * 256 + w * 64;
  f32x4 xa[4][8];
  ushort4 xbh[4][8];
#pragma unroll
  for (int nt = 0; nt < 4; ++nt)
#pragma unroll
    for (int O = 0; O < 8; ++O) {
      f32x4 v = *(const f32x4*)&x0[(rbase + nt * 16 + lm) * 128 + O * 16 + 4 * g];
      xa[nt][O] = v;
      uint64_t q = pack4(v[0], v[1], v[2], v[3]);
      ushort4 hq;
      *(uint64_t*)&hq = q;
      xbh[nt][O] = hq;
      int r = nt * 16 + lm;
      *(uint64_t*)(xsw + xs_off(r, O * 16 + 4 * g)) = q;
    }

  // Prologue: prefetch W chunks 0,1 into ring slots 0,1 (4 segs/wave/chunk).
#pragma unroll
  for (int pc = 0; pc < 2; ++pc) {
    const char* src = (const char*)wp + pc * 16384;
#pragma unroll
    for (int q = 0; q < 4; ++q) {
      int seg = w * 4 + q;
      gload_lds16(src + seg * 1024 + lane * 16, Wbuf[pc] + seg * 1024);
    }
  }
  asm volatile("s_waitcnt vmcnt(4) lgkmcnt(0)" ::: "memory");
  __builtin_amdgcn_s_barrier();

#pragma unroll 1
  for (int it = 0; it < 80; ++it) {
    const int s = it & 3;
    const float wgt = (s == 0 || s == 3) ? (0.1f / 6.0f) : (0.1f / 3.0f);
    const float alph = (s < 2) ? 0.05f : 0.1f;

    // x^T B-frags (K_in=128), held for the whole eval.
    half8 X1[4][4];
#pragma unroll
    for (int nt = 0; nt < 4; ++nt)
#pragma unroll
      for (int ks = 0; ks < 4; ++ks)
        X1[nt][ks] =
            *(const half8*)(xsw + xs_off(nt * 16 + lm, ks * 32 + g * 8));

    f32x4 yacc[4][8];
#pragma unroll
    for (int nt = 0; nt < 4; ++nt)
#pragma unroll
      for (int O = 0; O < 8; ++O) yacc[nt][O] = f32x4{0.f, 0.f, 0.f, 0.f};

#pragma unroll
    for (int c = 0; c < 16; ++c) {
      // h(c-1) B-frags (wave-private; written last iteration).
      half8 Hp[4];
      if (c > 0) {
#pragma unroll
        for (int nt = 0; nt < 4; ++nt)
          Hp[nt] = *(const half8*)(hsw + hs_off(nt * 16 + lm, g * 8));
      }

      // Prefetch chunk (c+2)&15 into ring slot (c+2)&3.
      {
        const int cn = (c + 2) & 15;
        char* buf = Wbuf[(c + 2) & 3];
        const char* src = (const char*)wp + cn * 16384;
#pragma unroll
        for (int q = 0; q < 4; ++q) {
          int seg = w * 4 + q;
          gload_lds16(src + seg * 1024 + lane * 16, buf + seg * 1024);
        }
      }

      // GEMM2'(c-1): y^T += W2T(c-1) x h^T(c-1). 8 O x 4 nt = 32 MFMA.
      if (c > 0) {
        const char* Wp = Wbuf[(c + 3) & 3];  // == (c-1)&3
#pragma unroll
        for (int O = 0; O < 8; ++O) {
          half8 wa = *(const half8*)(Wp + 8192 + O * 1024 + lane * 16);
#pragma unroll
          for (int nt = 0; nt < 4; ++nt)
            yacc[nt][O] =
                __builtin_amdgcn_mfma_f32_16x16x32_f16(wa, Hp[nt], yacc[nt][O], 0, 0, 0);
        }
      }

      // GEMM1'(c): h^T (hid 32 x batch 64). 2T x 4ks x 4nt = 32 MFMA.
      const char* Wb = Wbuf[c & 3];
#pragma unroll
      for (int T = 0; T < 2; ++T) {
        f32x4 hc[4];
#pragma unroll
        for (int nt = 0; nt < 4; ++nt) hc[nt] = f32x4{0.f, 0.f, 0.f, 0.f};
#pragma unroll
        for (int ks = 0; ks < 4; ++ks) {
          half8 wa = *(const half8*)(Wb + (T * 4 + ks) * 1024 + lane * 16);
#pragma unroll
          for (int nt = 0; nt < 4; ++nt)
            hc[nt] = __builtin_amdgcn_mfma_f32_16x16x32_f16(wa, X1[nt][ks], hc[nt], 0, 0, 0);
        }
        f32x4 bb = *(const f32x4*)&b1s[c * 32 + T * 16 + 4 * g];
#pragma unroll
        for (int nt = 0; nt < 4; ++nt) {
          uint64_t p = pack4(fmaxf(hc[nt][0] + bb[0], 0.f), fmaxf(hc[nt][1] + bb[1], 0.f),
                             fmaxf(hc[nt][2] + bb[2], 0.f), fmaxf(hc[nt][3] + bb[3], 0.f));
          *(uint64_t*)(hsw + hs_off(nt * 16 + lm, T * 16 + 4 * g)) = p;
        }
      }

      // Counted wait: outstanding {c+1, c+2} x4 loads; ensure c+1 landed.
      asm volatile("s_waitcnt vmcnt(4)" ::: "memory");
      __builtin_amdgcn_s_barrier();
    }

    // Tail GEMM2'(15).
    {
      half8 Hl[4];
#pragma unroll
      for (int nt = 0; nt < 4; ++nt)
        Hl[nt] = *(const half8*)(hsw + hs_off(nt * 16 + lm, g * 8));
      const char* Wp = Wbuf[3];  // 15 & 3
#pragma unroll
      for (int O = 0; O < 8; ++O) {
        half8 wa = *(const half8*)(Wp + 8192 + O * 1024 + lane * 16);
#pragma unroll
        for (int nt = 0; nt < 4; ++nt)
          yacc[nt][O] =
              __builtin_amdgcn_mfma_f32_16x16x32_f16(wa, Hl[nt], yacc[nt][O], 0, 0, 0);
      }
    }

    // RK4 combine; write next x_in (packed b64) into xs.
#pragma unroll
    for (int nt = 0; nt < 4; ++nt)
#pragma unroll
      for (int O = 0; O < 8; ++O) {
        f32x4 bb2 = *(const f32x4*)&b2s[O * 16 + 4 * g];
        f32x4 k = yacc[nt][O];
#pragma unroll
        for (int j = 0; j < 4; ++j) k[j] += bb2[j];
        xa[nt][O] += wgt * k;
        uint64_t q;
        if (s == 3) {
          f32x4 v = xa[nt][O];
          q = pack4(v[0], v[1], v[2], v[3]);
          ushort4 hq;
          *(uint64_t*)&hq = q;
          xbh[nt][O] = hq;
        } else {
          ushort4 xq = xbh[nt][O];
          q = pack4(h2f(xq.x) + alph * k[0], h2f(xq.y) + alph * k[1],
                    h2f(xq.z) + alph * k[2], h2f(xq.w) + alph * k[3]);
        }
        *(uint64_t*)(xsw + xs_off(nt * 16 + lm, O * 16 + 4 * g)) = q;
      }
  }

#pragma unroll
  for (int nt = 0; nt < 4; ++nt)
#pragma unroll
    for (int O = 0; O < 8; ++O)
      *(f32x4*)&out[(rbase + nt * 16 + lm) * 128 + O * 16 + 4 * g] = xa[nt][O];
}

extern "C" void kernel_launch(void* const* d_in, const int* in_sizes, int n_in,
                              void* d_out, int out_size, void* d_ws, size_t ws_size,
                              hipStream_t stream) {
  const float* x0 = (const float*)d_in[0];
  const float* W1 = (const float*)d_in[1];
  const float* b1 = (const float*)d_in[2];
  const float* W2 = (const float*)d_in[3];
  const float* b2 = (const float*)d_in[4];
  float* out = (float*)d_out;

  unsigned short* wp = (unsigned short*)d_ws;  // 256 frags * 1KB = 256KB

  pack_w<<<64, 256, 0, stream>>>(W1, W2, wp);
  node_rk4<<<256, 256, 0, stream>>>(x0, b1, b2, wp, out);
}

// Round 10
// 2158.853 us; speedup vs baseline: 4.6653x; 2.0434x over previous
//
#include <hip/hip_runtime.h>
#include <stdint.h>

// ===================== Round 10 =====================
// R6 outer structure (256 blk x 8 waves, W ring-4 via global_load_lds,
// counted vmcnt(2)+s_barrier, GEMM2 one chunk behind) with REGISTER-
// DIRECT h: GEMM1' (swapped) C/D regs feed GEMM2 (unswapped) A-frags
// via the k-permutation pi(g,j) = (j<4 ? 4g+j : 16+4g+j-4) baked into
// W2's packed B-frags. h never touches LDS (hst deleted). State/yacc
// flip to unswapped layout; x-scatter to xs once per eval (b16s).
// Predict: 1550-1750us, MfmaUtil 33-37, conflicts <=2.5e7, absmax 0.03125.
// ====================================================

typedef _Float16 half8 __attribute__((ext_vector_type(8)));
typedef float f32x4 __attribute__((ext_vector_type(4)));
typedef __attribute__((address_space(3))) char lchar;
typedef __attribute__((address_space(1))) char gchar;

#define XSTR 136  // shorts per xs row (128 + 8 pad) = 272B

static __device__ __forceinline__ void gload_lds16(const void* g, void* l) {
  __builtin_amdgcn_global_load_lds((const gchar*)g, (lchar*)l, 16, 0, 0);
}

static __device__ __forceinline__ unsigned short f2h(float x) {
  union { _Float16 h; unsigned short u; } cv;
  cv.h = (_Float16)x;
  return cv.u;
}
static __device__ __forceinline__ float h2f(unsigned short u) {
  union { unsigned short u; _Float16 h; } cv;
  cv.u = u;
  return (float)cv.h;
}
static __device__ __forceinline__ uint64_t pack4(float a, float b, float c, float d) {
  union { _Float16 h[4]; uint64_t q; } cv;
  cv.h[0] = (_Float16)a; cv.h[1] = (_Float16)b;
  cv.h[2] = (_Float16)c; cv.h[3] = (_Float16)d;
  return cv.q;
}

// Prepack weights as fp16 MFMA fragment streams, 16 chunks of 32 hid,
// chunk c at wp + c*16384:
//  [0,8K): W1T A-frags (swapped GEMM1), f = T*4+ks, natural k:
//          lane l holds A[m=hid c*32+T*16+(l&15)][k_in=ks*32+(l>>4)*8+j].
//  [8K,16K): W2 B-frags (unswapped GEMM2) with pi-permuted k:
//          f = 8+O; lane l slot j holds B[k_hid=c*32+pi(g,j)][n=out O*16+(l&15)]
//          where pi(g,j) = (j<4 ? 4g+j : 16+4g+(j-4)), g=(l>>4).
//          pi matches the slot layout of GEMM1's C/D regs packed as
//          [T0 rows 4g..4g+3 | T1 rows 4g..4g+3] -> h stays in registers.
__global__ void pack_w(const float* __restrict__ W1, const float* __restrict__ W2,
                       unsigned short* __restrict__ wp) {
  int id = blockIdx.x * 256 + threadIdx.x;  // 0..16383
  int lane = id & 63, fid = (id >> 6) & 255;
  int g = lane >> 4, lm = lane & 15;
  int c = fid >> 4, f = fid & 15;
  if (f < 8) {
    int T = f >> 2, ks = f & 3;
    int hid = c * 32 + T * 16 + lm;
#pragma unroll
    for (int j = 0; j < 8; ++j) {
      int kin = ks * 32 + g * 8 + j;
      wp[fid * 512 + lane * 8 + j] = f2h(W1[kin * 512 + hid]);
    }
  } else {
    int O = f - 8;
    int of = O * 16 + lm;
#pragma unroll
    for (int j = 0; j < 8; ++j) {
      int khl = (j < 4) ? (4 * g + j) : (16 + 4 * g + (j - 4));  // pi(g,j)
      wp[fid * 512 + lane * 8 + j] = f2h(W2[(c * 32 + khl) * 128 + of]);
    }
  }
}

__global__ __launch_bounds__(512, 2) void node_rk4(
    const float* __restrict__ x0, const float* __restrict__ b1,
    const float* __restrict__ b2, const unsigned short* __restrict__ wp,
    float* __restrict__ out) {
  // LDS: 64K W ring + 68K xs + 2.5K biases = 134.5 KB (no hst).
  __shared__ char Wbuf[4][16384];
  __shared__ __align__(16) unsigned short xs[8][32][XSTR];  // x_in fp16, [batch][feat]
  __shared__ float b1s[512];
  __shared__ float b2s[128];

  const int tid = threadIdx.x;
  const int w = tid >> 6, lane = tid & 63;
  const int g = lane >> 4, lm = lane & 15;

  b1s[tid] = b1[tid];
  if (tid < 128) b2s[tid] = b2[tid];

  // UNSWAPPED state layout: lane (g,lm) holds rows mt*16+4g+j (j=0..3),
  // out/feat col O*16+lm. xa fp32 accumulator, xbh fp16 step base.
  const int rbase = blockIdx.x * 256 + w * 32;
  f32x4 xa[2][8];
  ushort4 xbh[2][8];
#pragma unroll
  for (int mt = 0; mt < 2; ++mt)
#pragma unroll
    for (int O = 0; O < 8; ++O) {
      f32x4 v;
#pragma unroll
      for (int j = 0; j < 4; ++j)
        v[j] = x0[(rbase + mt * 16 + 4 * g + j) * 128 + O * 16 + lm];
      xa[mt][O] = v;
      ushort4 hq;
      hq.x = f2h(v[0]); hq.y = f2h(v[1]); hq.z = f2h(v[2]); hq.w = f2h(v[3]);
      xbh[mt][O] = hq;
      // scatter x_in for eval 0 into xs[batch][feat]
      unsigned short* xr = &xs[w][mt * 16 + 4 * g][O * 16 + lm];
      xr[0] = hq.x; xr[XSTR] = hq.y; xr[2 * XSTR] = hq.z; xr[3 * XSTR] = hq.w;
    }

  // Prologue: prefetch W chunks 0,1 into ring slots 0,1 (2 x 1KB per wave).
#pragma unroll
  for (int pc = 0; pc < 2; ++pc) {
    const char* src = (const char*)wp + pc * 16384;
#pragma unroll
    for (int q = 0; q < 2; ++q) {
      int seg = w * 2 + q;
      gload_lds16(src + seg * 1024 + lane * 16, Wbuf[pc] + seg * 1024);
    }
  }
  asm volatile("s_waitcnt vmcnt(2) lgkmcnt(0)" ::: "memory");
  __builtin_amdgcn_s_barrier();

#pragma unroll 1
  for (int it = 0; it < 80; ++it) {
    const int s = it & 3;
    const float wgt = (s == 0 || s == 3) ? (0.1f / 6.0f) : (0.1f / 3.0f);
    const float alph = (s < 2) ? 0.05f : 0.1f;

    // x^T B-frags for swapped GEMM1 (K_in=128), held all eval:
    // lane (g,lm): batch col nt*16+lm, k_in = ks*32 + g*8 + j.
    half8 X1[2][4];
#pragma unroll
    for (int nt = 0; nt < 2; ++nt)
#pragma unroll
      for (int ks = 0; ks < 4; ++ks)
        X1[nt][ks] = *(const half8*)&xs[w][nt * 16 + lm][ks * 32 + g * 8];

    f32x4 yacc[2][8];
#pragma unroll
    for (int mt = 0; mt < 2; ++mt)
#pragma unroll
      for (int O = 0; O < 8; ++O) yacc[mt][O] = f32x4{0.f, 0.f, 0.f, 0.f};

    half8 hpk[2][2];  // [c&1][mt]: pi-packed h A-frags (register-direct)

#pragma unroll
    for (int c = 0; c < 16; ++c) {
      // Prefetch chunk (c+2)&15 into ring slot (c+2)&3.
      {
        const int cn = (c + 2) & 15;
        char* buf = Wbuf[(c + 2) & 3];
        const char* src = (const char*)wp + cn * 16384;
#pragma unroll
        for (int q = 0; q < 2; ++q) {
          int seg = w * 2 + q;
          gload_lds16(src + seg * 1024 + lane * 16, buf + seg * 1024);
        }
      }

      __builtin_amdgcn_s_setprio(1);
      // GEMM2(c-1), unswapped: y[batch][out] += h(A, regs) x W2T-frag(B).
      if (c > 0) {
        const char* Wp = Wbuf[(c + 3) & 3];  // == (c-1)&3
#pragma unroll
        for (int O = 0; O < 8; ++O) {
          half8 w2f = *(const half8*)(Wp + 8192 + O * 1024 + lane * 16);
          yacc[0][O] = __builtin_amdgcn_mfma_f32_16x16x32_f16(hpk[(c - 1) & 1][0], w2f,
                                                              yacc[0][O], 0, 0, 0);
          yacc[1][O] = __builtin_amdgcn_mfma_f32_16x16x32_f16(hpk[(c - 1) & 1][1], w2f,
                                                              yacc[1][O], 0, 0, 0);
        }
      }

      // GEMM1'(c), swapped: h[hid][batch] = W1T(A) x x^T(B). 4 indep chains.
      const char* Wb = Wbuf[c & 3];
      f32x4 hacc[2][2];  // [T][nt]
#pragma unroll
      for (int T = 0; T < 2; ++T)
#pragma unroll
        for (int nt = 0; nt < 2; ++nt) hacc[T][nt] = f32x4{0.f, 0.f, 0.f, 0.f};
#pragma unroll
      for (int T = 0; T < 2; ++T)
#pragma unroll
        for (int ks = 0; ks < 4; ++ks) {
          half8 wa = *(const half8*)(Wb + (T * 4 + ks) * 1024 + lane * 16);
          hacc[T][0] =
              __builtin_amdgcn_mfma_f32_16x16x32_f16(wa, X1[0][ks], hacc[T][0], 0, 0, 0);
          hacc[T][1] =
              __builtin_amdgcn_mfma_f32_16x16x32_f16(wa, X1[1][ks], hacc[T][1], 0, 0, 0);
        }
      __builtin_amdgcn_s_setprio(0);

      // bias+relu, pack into pi-slot order [T0 j0..3 | T1 j0..3] -> A-frags.
      f32x4 bb0 = *(const f32x4*)&b1s[c * 32 + 4 * g];
      f32x4 bb1 = *(const f32x4*)&b1s[c * 32 + 16 + 4 * g];
#pragma unroll
      for (int nt = 0; nt < 2; ++nt) {
        union { uint64_t q[2]; half8 h; } u;
        u.q[0] = pack4(fmaxf(hacc[0][nt][0] + bb0[0], 0.f),
                       fmaxf(hacc[0][nt][1] + bb0[1], 0.f),
                       fmaxf(hacc[0][nt][2] + bb0[2], 0.f),
                       fmaxf(hacc[0][nt][3] + bb0[3], 0.f));
        u.q[1] = pack4(fmaxf(hacc[1][nt][0] + bb1[0], 0.f),
                       fmaxf(hacc[1][nt][1] + bb1[1], 0.f),
                       fmaxf(hacc[1][nt][2] + bb1[2], 0.f),
                       fmaxf(hacc[1][nt][3] + bb1[3], 0.f));
        hpk[c & 1][nt] = u.h;
      }

      // Counted wait: outstanding {c+1,c+2} x2 loads; ensure c+1 landed.
      asm volatile("s_waitcnt vmcnt(2)" ::: "memory");
      __builtin_amdgcn_s_barrier();
    }

    // Tail GEMM2(15) from registers.
    {
      const char* Wp = Wbuf[3];  // 15 & 3
#pragma unroll
      for (int O = 0; O < 8; ++O) {
        half8 w2f = *(const half8*)(Wp + 8192 + O * 1024 + lane * 16);
        yacc[0][O] =
            __builtin_amdgcn_mfma_f32_16x16x32_f16(hpk[1][0], w2f, yacc[0][O], 0, 0, 0);
        yacc[1][O] =
            __builtin_amdgcn_mfma_f32_16x16x32_f16(hpk[1][1], w2f, yacc[1][O], 0, 0, 0);
      }
    }

    // RK4 combine (unswapped layout); scatter next x_in into xs (b16s).
#pragma unroll
    for (int mt = 0; mt < 2; ++mt)
#pragma unroll
      for (int O = 0; O < 8; ++O) {
        float bb2 = b2s[O * 16 + lm];
        f32x4 k = yacc[mt][O];
#pragma unroll
        for (int j = 0; j < 4; ++j) k[j] += bb2;
        xa[mt][O] += wgt * k;
        ushort4 hq;
        if (s == 3) {
          f32x4 v = xa[mt][O];
          hq.x = f2h(v[0]); hq.y = f2h(v[1]); hq.z = f2h(v[2]); hq.w = f2h(v[3]);
          xbh[mt][O] = hq;
        } else {
          ushort4 xq = xbh[mt][O];
          hq.x = f2h(h2f(xq.x) + alph * k[0]);
          hq.y = f2h(h2f(xq.y) + alph * k[1]);
          hq.z = f2h(h2f(xq.z) + alph * k[2]);
          hq.w = f2h(h2f(xq.w) + alph * k[3]);
        }
        unsigned short* xr = &xs[w][mt * 16 + 4 * g][O * 16 + lm];
        xr[0] = hq.x; xr[XSTR] = hq.y; xr[2 * XSTR] = hq.z; xr[3 * XSTR] = hq.w;
      }
  }

#pragma unroll
  for (int mt = 0; mt < 2; ++mt)
#pragma unroll
    for (int O = 0; O < 8; ++O)
#pragma unroll
      for (int j = 0; j < 4; ++j)
        out[(rbase + mt * 16 + 4 * g + j) * 128 + O * 16 + lm] = xa[mt][O][j];
}

extern "C" void kernel_launch(void* const* d_in, const int* in_sizes, int n_in,
                              void* d_out, int out_size, void* d_ws, size_t ws_size,
                              hipStream_t stream) {
  const float* x0 = (const float*)d_in[0];
  const float* W1 = (const float*)d_in[1];
  const float* b1 = (const float*)d_in[2];
  const float* W2 = (const float*)d_in[3];
  const float* b2 = (const float*)d_in[4];
  float* out = (float*)d_out;

  unsigned short* wp = (unsigned short*)d_ws;  // 256 frags * 1KB = 256KB

  pack_w<<<64, 256, 0, stream>>>(W1, W2, wp);
  node_rk4<<<256, 512, 0, stream>>>(x0, b1, b2, wp, out);
}